// Round 10
// baseline (63.809 us; speedup 1.0000x reference)
//
#include <hip/hip_runtime.h>
#include <math.h>

#define N_I 1152
#define N_O 10
#define N_D 16
#define BLK 256
#define KPT 18            // i-rows per thread: 1152 / (BLK/4)
#define ROWS (N_O * N_D)  // 160 floats per i-row
#define NITEM 5           // o's per block: one half-b
#define NSLOT (N_I * 4)   // 4608 float4 LDS slots = 72 KB

// DPP quad_perm butterfly adds (pure VALU): xor1=0xB1, xor2=0x4E
__device__ __forceinline__ float qadd1(float x) {
    return x + __int_as_float(__builtin_amdgcn_update_dpp(
        0, __float_as_int(x), 0xB1, 0xF, 0xF, true));
}
__device__ __forceinline__ float qadd2(float x) {
    return x + __int_as_float(__builtin_amdgcn_update_dpp(
        0, __float_as_int(x), 0x4E, 0xF, 0xF, true));
}
// Workgroup barrier that does NOT drain vmcnt: in-flight global_load_lds
// prefetch survives across it (the one thing __syncthreads would kill).
__device__ __forceinline__ void lgkm_barrier() {
    asm volatile("s_waitcnt lgkmcnt(0)" ::: "memory");
    __builtin_amdgcn_s_barrier();
    __builtin_amdgcn_sched_barrier(0);
}

// Persistent balanced grid: B*2 = 512 blocks = exactly 2/CU, 5 items each.
// Next item prefetched via global_load_lds DMA (zero VGPR cost -> no
// allocator fight, rounds 5/6/8 lesson). DMA streams during compute, so
// phase-locked VALU windows no longer idle the HBM pipe. Only vmcnt(0)
// drain is the __syncthreads at the item boundary (= DMA consumption).
__global__ __launch_bounds__(BLK, 2)
void caps_route(const float* __restrict__ u_hat, float* __restrict__ out)
{
    __shared__ float4 ubuf[NSLOT];      // 72 KB DMA prefetch buffer
    __shared__ float4 scr_s[2][4][4];   // [pingpong][wave][d4]
    __shared__ float  scr_e[2][4];

    const int tid  = threadIdx.x;
    const int wave = tid >> 6;
    const int lane = tid & 63;
    const int d4   = tid & 3;
    const int ig   = tid >> 2;    // 0..63

    const int bid = blockIdx.x;
    const int b   = bid >> 1;
    const int o0  = (bid & 1) * NITEM;

    const float* bbase = u_hat + (size_t)b * (N_I * ROWS) + (size_t)o0 * N_D;
    float* outb = out + ((size_t)b * N_O + o0) * N_D;

    // slot s = j*BLK+tid: row = s>>2, ch = s&3. LDS dst is wave-uniform
    // base + lane*16 (hardware requirement); global src is per-lane.
    auto issue_item = [&](int t) {
        __builtin_amdgcn_sched_barrier(0);
        const float* g0 = bbase + t * N_D;
        #pragma unroll
        for (int j = 0; j < KPT; ++j) {
            const int s = j * BLK + tid;
            const float* g = g0 + (size_t)(s >> 2) * ROWS + (size_t)(s & 3) * 4;
            float4* dst = ubuf + (j * BLK + (tid & ~63));
            __builtin_amdgcn_global_load_lds(
                (const __attribute__((address_space(1))) void*)g,
                (__attribute__((address_space(3))) void*)dst,
                16, 0, 0);
        }
        __builtin_amdgcn_sched_barrier(0);
    };

    issue_item(0);

    for (int t = 0; t < NITEM; ++t) {
        __syncthreads();   // drains vmcnt: item t's DMA landed, all waves here

        // LDS -> registers once (conflict-free: wave reads 1KB contiguous);
        // r=0 partial sums fused under the ds_read stream.
        float4 u[KPT];
        float4 s4 = make_float4(0.f, 0.f, 0.f, 0.f);
        #pragma unroll
        for (int k = 0; k < KPT; ++k) {
            u[k] = ubuf[((ig + (k << 6)) << 2) | d4];
            s4.x += u[k].x; s4.y += u[k].y;
            s4.z += u[k].z; s4.w += u[k].w;
        }
        lgkm_barrier();                       // all waves done reading ubuf
        if (t + 1 < NITEM) issue_item(t + 1); // next DMA in flight NOW

        float esum = (float)KPT;   // r=0: b==0 -> uniform weights, e_i = 1
        float4 vc = make_float4(0.f, 0.f, 0.f, 0.f);
        float4 v4;
        #pragma unroll
        for (int r = 0; r < 3; ++r) {
            if (r > 0) {
                s4 = make_float4(0.f, 0.f, 0.f, 0.f);
                esum = 0.0f;
                #pragma unroll
                for (int k = 0; k < KPT; ++k) {
                    float p = u[k].x*vc.x + u[k].y*vc.y
                            + u[k].z*vc.z + u[k].w*vc.w;
                    p = qadd1(p);             // DPP quad butterfly: 16-d dot
                    p = qadd2(p);
                    const float e = __expf(p);
                    esum += e;
                    s4.x += e*u[k].x; s4.y += e*u[k].y;
                    s4.z += e*u[k].z; s4.w += e*u[k].w;
                }
            }
            // reduce over the 16 ig-groups within the wave (lane bits 2..5)
            #pragma unroll
            for (int m = 4; m <= 32; m <<= 1) {
                s4.x += __shfl_xor(s4.x, m);
                s4.y += __shfl_xor(s4.y, m);
                s4.z += __shfl_xor(s4.z, m);
                s4.w += __shfl_xor(s4.w, m);
                esum += __shfl_xor(esum, m);
            }
            const int pp = r & 1;             // ping-pong: WAR-safe, 1 barrier
            if (lane < 4) {
                scr_s[pp][wave][lane] = s4;
                if (lane == 0) scr_e[pp][wave] = esum;
            }
            lgkm_barrier();                   // DMA stays in flight
            float4 st = make_float4(0.f, 0.f, 0.f, 0.f);
            float et = 0.f;
            #pragma unroll
            for (int w = 0; w < 4; ++w) {
                const float4 q = scr_s[pp][w][d4];
                st.x += q.x; st.y += q.y; st.z += q.z; st.w += q.w;
                et += scr_e[pp][w];
            }
            const float inv = 1.0f / et;      // softmax normalization folded
            st.x *= inv; st.y *= inv; st.z *= inv; st.w *= inv;
            float sq = st.x*st.x + st.y*st.y + st.z*st.z + st.w*st.w;
            sq = qadd1(sq);                   // full ||s||^2 across the quads
            sq = qadd2(sq);
            const float nrm = sqrtf(sq);
            const float f = nrm / (1.0f + sq);   // v = s*f
            v4.x = st.x*f; v4.y = st.y*f; v4.z = st.z*f; v4.w = st.w*f;
            vc.x += v4.x; vc.y += v4.y; vc.z += v4.z; vc.w += v4.w;
        }
        if (tid < 4)                          // wave0 lanes 0..3 = d4 0..3
            *(float4*)(outb + t * N_D + (tid << 2)) = v4;
    }
}

extern "C" void kernel_launch(void* const* d_in, const int* in_sizes, int n_in,
                              void* d_out, int out_size, void* d_ws, size_t ws_size,
                              hipStream_t stream)
{
    const float* u_hat = (const float*)d_in[0];
    float* out = (float*)d_out;
    const int B = in_sizes[0] / (N_I * N_O * N_D);
    hipLaunchKernelGGL(caps_route, dim3(B * 2), dim3(BLK), 0, stream, u_hat, out);
}

// Round 11
// 41.064 us; speedup vs baseline: 1.5539x; 1.5539x over previous
//
#include <hip/hip_runtime.h>
#include <math.h>

#define N_I 1152
#define N_O 10
#define N_D 16
#define BLK 256
#define KPT 18            // i-rows per thread: 1152 / (BLK/4)
#define ROWS (N_O * N_D)  // 160 floats per i-row
#define LOG2E 1.44269504088896340736f

// DPP quad_perm butterfly adds (pure VALU): xor1=0xB1, xor2=0x4E
__device__ __forceinline__ float qadd1(float x) {
    return x + __int_as_float(__builtin_amdgcn_update_dpp(
        0, __float_as_int(x), 0xB1, 0xF, 0xF, true));
}
__device__ __forceinline__ float qadd2(float x) {
    return x + __int_as_float(__builtin_amdgcn_update_dpp(
        0, __float_as_int(x), 0x4E, 0xF, 0xF, true));
}

// Barrier that waits only on LDS ops (lgkmcnt), NOT vmcnt: the prefetch
// global loads (register destinations) stay in flight across it. Registers
// are per-thread, so skipping the vmcnt drain is semantically safe; the
// "memory" clobber + asm ordering keeps ds ops on the right side.
__device__ __forceinline__ void lds_barrier() {
    asm volatile("s_waitcnt lgkmcnt(0)" ::: "memory");
    __builtin_amdgcn_s_barrier();
    __builtin_amdgcn_sched_barrier(0);
}

__device__ __forceinline__ const float* item_ptr(const float* u_hat, int wid,
                                                 int ig, int d4)
{
    const int b = wid / N_O;
    const int o = wid - b * N_O;
    return u_hat + (size_t)b * (N_I * ROWS) + (size_t)o * N_D
                 + (size_t)ig * ROWS + (size_t)(d4 << 2);
}

// One routing item from register tile u[]. If PRE, the next item's loads
// refill u[] in place right after r2's last use (round-6-proven codegen:
// single tile, VGPR~100, no remat). ppb staggers the scratch ping-pong
// parity across items so 1 barrier/r stays WAR-safe (3 r's per item).
template<bool PRE>
__device__ __forceinline__ void route_item(
    float4 (&u)[KPT], const float* __restrict__ gnext,
    float* __restrict__ outp, int tid, int wave, int lane, int d4, int ppb,
    float4 (*scr_s)[4][4], float (*scr_e)[4])
{
    float4 vc = make_float4(0.f, 0.f, 0.f, 0.f);
    float4 v4;
    #pragma unroll
    for (int r = 0; r < 3; ++r) {
        float4 s4 = make_float4(0.f, 0.f, 0.f, 0.f);
        float esum;
        if (r == 0) {
            #pragma unroll
            for (int k = 0; k < KPT; ++k) {   // staggered vmcnt consumption
                s4.x += u[k].x; s4.y += u[k].y;
                s4.z += u[k].z; s4.w += u[k].w;
            }
            esum = (float)KPT;   // b == 0 -> uniform weights, e_i = 1
        } else {
            esum = 0.f;
            const float4 vl = make_float4(vc.x*LOG2E, vc.y*LOG2E,
                                          vc.z*LOG2E, vc.w*LOG2E);
            #pragma unroll
            for (int k = 0; k < KPT; ++k) {
                float p = u[k].x*vl.x + u[k].y*vl.y + u[k].z*vl.z + u[k].w*vl.w;
                p = qadd1(p);             // DPP quad butterfly: 16-dim dot
                p = qadd2(p);
                const float e = exp2f(p); // native v_exp_f32 (log2e folded)
                esum += e;
                s4.x += e*u[k].x; s4.y += e*u[k].y;
                s4.z += e*u[k].z; s4.w += e*u[k].w;
            }
        }
        if (PRE && r == 2) {
            // u[] dead after r2's k-loop: refill with the next item NOW.
            __builtin_amdgcn_sched_barrier(0);   // don't hoist above r2
            #pragma unroll
            for (int k = 0; k < KPT; ++k)
                u[k] = *(const float4*)(gnext + (size_t)(k << 6) * ROWS);
            __builtin_amdgcn_sched_barrier(0);   // don't sink below
        }
        // reduce over the 16 ig-groups within the wave (lane bits 2..5)
        #pragma unroll
        for (int m = 4; m <= 32; m <<= 1) {
            s4.x += __shfl_xor(s4.x, m);
            s4.y += __shfl_xor(s4.y, m);
            s4.z += __shfl_xor(s4.z, m);
            s4.w += __shfl_xor(s4.w, m);
            esum += __shfl_xor(esum, m);
        }
        const int pp = (ppb + r) & 1;     // alternates across items too
        if (lane < 4) {
            scr_s[pp][wave][lane] = s4;
            if (lane == 0) scr_e[pp][wave] = esum;
        }
        lds_barrier();                    // prefetch stays in flight
        float4 st = make_float4(0.f, 0.f, 0.f, 0.f);
        float et = 0.f;
        #pragma unroll
        for (int w = 0; w < 4; ++w) {
            const float4 q = scr_s[pp][w][d4];
            st.x += q.x; st.y += q.y; st.z += q.z; st.w += q.w;
            et += scr_e[pp][w];
        }
        const float inv = 1.0f / et;      // softmax normalization folded
        st.x *= inv; st.y *= inv; st.z *= inv; st.w *= inv;
        float sq = st.x*st.x + st.y*st.y + st.z*st.z + st.w*st.w;
        sq = qadd1(sq);                   // full ||s||^2 across the 4 quads
        sq = qadd2(sq);
        const float nrm = sqrtf(sq);
        const float f = nrm / (1.0f + sq);   // v = sq*s/((1+sq)*nrm) = s*f
        v4.x = st.x*f; v4.y = st.y*f; v4.z = st.z*f; v4.w = st.w*f;
        vc.x += v4.x; vc.y += v4.y; vc.z += v4.z; vc.w += v4.w;
    }
    if (tid < 4)                          // wave0 lanes 0..3 hold d4=0..3
        *(float4*)(outp + (tid << 2)) = v4;
}

// Balanced 2-item blocks: grid = B*5 = 1280, item0 = slot, item1 = slot+nwg.
// 1280 > 1024 resident -> staggered block starts desynchronize the residual
// no-VMEM windows. XCD chunking keeps o-adjacent wids on one XCD for the
// cross-o 128B-line L2 dedup (round-4 FETCH evidence: ~12% saved).
__global__ __launch_bounds__(BLK, 4)
void caps_route(const float* __restrict__ u_hat, float* __restrict__ out)
{
    __shared__ float4 scr_s[2][4][4];   // [pingpong][wave][d4]
    __shared__ float  scr_e[2][4];

    const int tid  = threadIdx.x;
    const int wave = tid >> 6;
    const int lane = tid & 63;
    const int d4   = tid & 3;
    const int ig   = tid >> 2;    // 0..63

    const int bid = blockIdx.x;
    const int nwg = gridDim.x;
    int slot = bid;
    if ((nwg & 7) == 0) slot = (bid & 7) * (nwg >> 3) + (bid >> 3);
    const int wid0 = slot;
    const int wid1 = slot + nwg;

    const float* g0 = item_ptr(u_hat, wid0, ig, d4);
    const float* g1 = item_ptr(u_hat, wid1, ig, d4);

    float4 u[KPT];
    #pragma unroll
    for (int k = 0; k < KPT; ++k)
        u[k] = *(const float4*)(g0 + (size_t)(k << 6) * ROWS);

    route_item<true >(u, g1, out + (size_t)wid0 * N_D,
                      tid, wave, lane, d4, 0, scr_s, scr_e);
    route_item<false>(u, (const float*)0, out + (size_t)wid1 * N_D,
                      tid, wave, lane, d4, 3, scr_s, scr_e);
}

extern "C" void kernel_launch(void* const* d_in, const int* in_sizes, int n_in,
                              void* d_out, int out_size, void* d_ws, size_t ws_size,
                              hipStream_t stream)
{
    const float* u_hat = (const float*)d_in[0];
    float* out = (float*)d_out;
    const int B = in_sizes[0] / (N_I * N_O * N_D);
    hipLaunchKernelGGL(caps_route, dim3(B * N_O / 2), dim3(BLK), 0, stream,
                       u_hat, out);
}

// Round 12
// 33.673 us; speedup vs baseline: 1.8949x; 1.2195x over previous
//
#include <hip/hip_runtime.h>
#include <math.h>

#define N_I 1152
#define N_O 10
#define N_D 16
#define BLK 256
#define KPT 18            // i-rows per thread: 1152 / (BLK/4)
#define ROWS (N_O * N_D)  // 160 floats per i-row

// DPP quad_perm butterfly adds (pure VALU, replaces ds_swizzle __shfl_xor):
// xor1 = quad_perm(1,0,3,2) = 0xB1 ; xor2 = quad_perm(2,3,0,1) = 0x4E
__device__ __forceinline__ float qadd1(float x) {
    return x + __int_as_float(__builtin_amdgcn_update_dpp(
        0, __float_as_int(x), 0xB1, 0xF, 0xF, true));
}
__device__ __forceinline__ float qadd2(float x) {
    return x + __int_as_float(__builtin_amdgcn_update_dpp(
        0, __float_as_int(x), 0x4E, 0xF, 0xF, true));
}

// FINAL (round-9 revert): one-shot one-item blocks. Rationale from the
// session's ablation ladder:
//  - u[18] tile in registers (72 data VGPRs) — LDS staging is slower
//    (r1: 46.5us) and global_load_lds DMA is ~2x slower (r10: 63.8us).
//  - ONE item per block: the HW dispatcher's block churn overlaps one
//    block's compute with fresh blocks' loads better than any in-kernel
//    prefetch (r5/r6/r8/r11 all regressed: allocator remat or late issue).
//  - launch_bounds(256,4): 128-VGPR cap, 4 blocks/CU, allocator-proven.
//  - DPP quad ops + 1 barrier/r + register vc: compute window shrunk
//    (r9: 35.1 -> 33.7us).
// 33.7us = 5.6 TB/s effective = 89% of the 6.29 TB/s measured copy ceiling;
// FETCH ~ one pass of the 189 MB input -> traffic-optimal, time-bound.
__global__ __launch_bounds__(BLK, 4)
void caps_route(const float* __restrict__ u_hat, float* __restrict__ out)
{
    __shared__ float4 scr_s[2][4][4];   // [pingpong][wave][d4]
    __shared__ float  scr_e[2][4];      // [pingpong][wave]

    const int tid  = threadIdx.x;
    const int wave = tid >> 6;
    const int lane = tid & 63;
    const int d4   = tid & 3;
    const int ig   = tid >> 2;    // 0..63

    // XCD-aware swizzle: consecutive wids (same b, adjacent o) on one XCD.
    const int bid = blockIdx.x;
    const int nwg = gridDim.x;
    int wid = bid;
    if ((nwg & 7) == 0) wid = (bid & 7) * (nwg >> 3) + (bid >> 3);
    const int b = wid / N_O;
    const int o = wid - b * N_O;

    const float* g = u_hat + (size_t)b * (N_I * ROWS) + (size_t)o * N_D
                   + (size_t)ig * ROWS + (size_t)(d4 << 2);

    // ---- global -> registers; r=0 partial sums fused under vmcnt ----
    float4 u[KPT];
    float4 s4 = make_float4(0.f, 0.f, 0.f, 0.f);
    #pragma unroll
    for (int k = 0; k < KPT; ++k) {
        u[k] = *(const float4*)(g + (size_t)(k << 6) * ROWS);
        s4.x += u[k].x; s4.y += u[k].y;
        s4.z += u[k].z; s4.w += u[k].w;
    }
    float esum = (float)KPT;     // r=0: b == 0 -> uniform weights, e_i = 1
    float4 vc = make_float4(0.f, 0.f, 0.f, 0.f);
    float4 v4;

    #pragma unroll
    for (int r = 0; r < 3; ++r) {
        if (r > 0) {
            // fused: t_i = u_i . vcum ; e = exp(t_i); s += e*u ; esum += e
            s4 = make_float4(0.f, 0.f, 0.f, 0.f);
            esum = 0.0f;
            #pragma unroll
            for (int k = 0; k < KPT; ++k) {
                float p = u[k].x*vc.x + u[k].y*vc.y + u[k].z*vc.z + u[k].w*vc.w;
                p = qadd1(p);             // DPP quad butterfly: 16-dim dot
                p = qadd2(p);
                const float e = __expf(p);
                esum += e;
                s4.x += e*u[k].x; s4.y += e*u[k].y;
                s4.z += e*u[k].z; s4.w += e*u[k].w;
            }
        }
        // reduce over the 16 ig-groups within the wave (lane bits 2..5)
        #pragma unroll
        for (int m = 4; m <= 32; m <<= 1) {
            s4.x += __shfl_xor(s4.x, m);
            s4.y += __shfl_xor(s4.y, m);
            s4.z += __shfl_xor(s4.z, m);
            s4.w += __shfl_xor(s4.w, m);
            esum += __shfl_xor(esum, m);
        }
        const int pp = r & 1;             // ping-pong: WAR safe w/ 1 barrier
        if (lane < 4) {
            scr_s[pp][wave][lane] = s4;
            if (lane == 0) scr_e[pp][wave] = esum;
        }
        __syncthreads();
        // ALL lanes: combine the 4 wave-partials for their own d4 quad.
        float4 st = make_float4(0.f, 0.f, 0.f, 0.f);
        float et = 0.f;
        #pragma unroll
        for (int w = 0; w < 4; ++w) {
            const float4 t = scr_s[pp][w][d4];
            st.x += t.x; st.y += t.y; st.z += t.z; st.w += t.w;
            et += scr_e[pp][w];
        }
        const float inv = 1.0f / et;      // softmax normalization folded
        st.x *= inv; st.y *= inv; st.z *= inv; st.w *= inv;
        float sq = st.x*st.x + st.y*st.y + st.z*st.z + st.w*st.w;
        sq = qadd1(sq);                   // full ||s||^2 across the 4 quads
        sq = qadd2(sq);
        const float nrm = sqrtf(sq);
        const float f = nrm / (1.0f + sq);   // v = sq*s/((1+sq)*nrm) = s*f
        v4.x = st.x*f; v4.y = st.y*f; v4.z = st.z*f; v4.w = st.w*f;
        if (r < 2) {                      // logit state in REGISTERS
            vc.x += v4.x; vc.y += v4.y; vc.z += v4.z; vc.w += v4.w;
        }
    }
    if (tid < 4)                          // wave0 lanes 0..3 hold d4=0..3
        *(float4*)(out + (size_t)wid * N_D + (tid << 2)) = v4;
}

extern "C" void kernel_launch(void* const* d_in, const int* in_sizes, int n_in,
                              void* d_out, int out_size, void* d_ws, size_t ws_size,
                              hipStream_t stream)
{
    const float* u_hat = (const float*)d_in[0];
    float* out = (float*)d_out;
    const int B = in_sizes[0] / (N_I * N_O * N_D);
    hipLaunchKernelGGL(caps_route, dim3(B * N_O), dim3(BLK), 0, stream, u_hat, out);
}